// Round 4
// baseline (120.194 us; speedup 1.0000x reference)
//
#include <hip/hip_runtime.h>
#include <hip/hip_bf16.h>

// QKVAttentionLegacy: qkv (4,3072,1024) fp32, 16 heads, ch=64.
// R12 = R11 restructured to 1024-thr blocks, grid 256 (4 t-tiles x 64 bh):
//  - per-CU staging traffic/cvt halves (one 32KB K+V tile per iter, was two);
//    K/V chip reuse 8x->4x and t-siblings of a bh share an XCD (b, b+64 same b&7).
//  - waves 0-3 stage K, 4-7 stage V, 8-15 pure compute (16 waves = 8 g x 2 sh).
//  - Q loaded global->regs directly (coalesced over t); q_s deleted; LDS 43KB.
//  - epilogue O-exchange in two 32KB passes over retired k0/k1/v1/v2 (v0 = final
//    PV buffer kept out of the exchange region).
// Core math identical to R11 (verified): 32x32x16 MFMAs, sigma-permuted K rows
// (swap bits 2<->3) -> PV B-frag = pk(St[2d],St[2d+1]) with identical reg
// indices in both lane halves (no permlane, no LDS for P); kap bank swizzles;
// PV one tile behind; V triple-buffered, K double, ONE barrier/iter.

typedef __bf16 bf16_8 __attribute__((ext_vector_type(8)));
typedef __bf16 bf16_4 __attribute__((ext_vector_type(4)));
typedef float floatx4 __attribute__((ext_vector_type(4)));
typedef float floatx16 __attribute__((ext_vector_type(16)));

#define NTHREADS 1024
#define STR 64               // bf16 elems per LDS row (128 B, swizzle not pad)
#define NSTEPS 16

#if __has_builtin(__builtin_amdgcn_exp2f)
#define EXP2(x) __builtin_amdgcn_exp2f(x)
#else
#define EXP2(x) exp2f(x)
#endif
// (1/8)*log2(e): qk scale + exp->exp2, folded into Q load (one bf16 rounding).
#define QSCALE 0.18033688011112042f

// LDS: k0 @0 | k1 @8192 | v1 @16384 | v2 @24576 | v0 @32768 (each 8192)
// epilogue: xo 32KB @0 (two passes, over k0/k1/v1/v2; v0 = final-PV buffer,
// untouched), xl @40960 (2KB)
#define LDS_BYTES 43008

#define ZERO16 (floatx16){0.f,0.f,0.f,0.f,0.f,0.f,0.f,0.f,0.f,0.f,0.f,0.f,0.f,0.f,0.f,0.f}

__device__ __forceinline__ int kap(int row) { return ((row >> 1) + (row >> 4)) & 7; }
// swap bits 2<->3 (keep 0,1,4,5); self-inverse. K s-row -> LDS row relabeling.
__device__ __forceinline__ int sigma_row(int s) {
    return (s & 0x33) | ((s & 4) << 1) | ((s & 8) >> 1);
}

__device__ __forceinline__ unsigned pk_bf16(float a, float b) {
    unsigned r;
    asm("v_cvt_pk_bf16_f32 %0, %1, %2" : "=v"(r) : "v"(a), "v"(b));
    return r;
}

union U8 { unsigned u[4]; bf16_8 v; };

__device__ __forceinline__ void write_k(__bf16* kn, const float4* r, int si, int sG) {
    #pragma unroll
    for (int rr = 0; rr < 4; ++rr) {
        int srow = si * 4 + rr;
        int m = sigma_row(srow);          // permuted LDS row
        bf16_4 w;
        w[0] = (__bf16)((const float*)&r[0])[rr];
        w[1] = (__bf16)((const float*)&r[1])[rr];
        w[2] = (__bf16)((const float*)&r[2])[rr];
        w[3] = (__bf16)((const float*)&r[3])[rr];
        *(bf16_4*)&kn[m * STR + ((sG ^ (kap(m) << 1)) << 2)] = w;
    }
}
__device__ __forceinline__ void write_v(__bf16* vn, const float4* r, int si, int c0) {
    #pragma unroll
    for (int jj = 0; jj < 4; ++jj) {
        int c = c0 + jj;
        bf16_4 w;
        w[0] = (__bf16)r[jj].x; w[1] = (__bf16)r[jj].y;
        w[2] = (__bf16)r[jj].z; w[3] = (__bf16)r[jj].w;
        *(bf16_4*)&vn[c * STR + ((si ^ (kap(c) << 1)) << 2)] = w;
    }
}

__global__ __launch_bounds__(NTHREADS, 4)
void attn_kernel(const float* __restrict__ qkv, float* __restrict__ out) {
    __shared__ char smem[LDS_BYTES];
    __bf16* k0  = (__bf16*)smem;
    __bf16* k1  = (__bf16*)(smem + 8192);
    __bf16* v1  = (__bf16*)(smem + 16384);
    __bf16* v2  = (__bf16*)(smem + 24576);
    __bf16* v0  = (__bf16*)(smem + 32768);

    const int tid  = threadIdx.x;
    const int wave = tid >> 6;           // 0..15
    const int lane = tid & 63;
    const int hv   = lane >> 5;          // lane half (k-octet select)
    const int l31  = lane & 31;
    const int g    = wave >> 1;          // t-group: rows [32g, 32g+32), g in 0..7
    const int sh   = wave & 1;           // s-half: [32sh, 32sh+32) of each tile

    const int bx = blockIdx.x;           // 256 = 4 t-tiles * 64 bh (bh fastest)
    const int bh = bx & 63;
    const int t0 = (bx >> 6) << 8;       // *256

    const float* qg = qkv + (size_t)bh * 196608;
    const float* kg = qg + 65536;
    const float* vg = qg + 131072;

    // staging split: waves 0-3 stage K, waves 4-7 stage V, 8-15 compute-only
    const int stager = (tid < 512);
    const int st = tid & 255;
    const int si = st & 15;
    const int sG = st >> 4;
    const int c0 = sG << 2;
    const float* gsrc = (tid < 256) ? kg : vg;

    // ---- Q B-frags straight from global (coalesced over t), scaled+packed ----
    // qf[kc] element e maps to c = 16*kc + 8*hv + e at t = t0 + 32g + l31.
    bf16_8 qf[4];
    {
        const int tq = t0 + g * 32 + l31;
        #pragma unroll
        for (int kc = 0; kc < 4; ++kc) {
            U8 w;
            #pragma unroll
            for (int d = 0; d < 4; ++d) {
                float f0 = qg[(16 * kc + 8 * hv + 2 * d) * 1024 + tq] * QSCALE;
                float f1 = qg[(16 * kc + 8 * hv + 2 * d + 1) * 1024 + tq] * QSCALE;
                w.u[d] = pk_bf16(f0, f1);
            }
            qf[kc] = w.v;
        }
    }

    // ---- K/V tile 0 ----
    if (stager) {
        float4 r4[4];
        #pragma unroll
        for (int jj = 0; jj < 4; ++jj)
            r4[jj] = *(const float4*)(gsrc + (c0 + jj) * 1024 + si * 4);
        if (tid < 256) write_k(k0, r4, si, sG);
        else           write_v(v0, r4, si, c0);
    }
    __syncthreads();

    floatx16 O0 = ZERO16, O1 = ZERO16;   // c-tiles [0,32), [32,64); partial over sh
    float l = 0.f;
    bf16_8 pfp0, pfp1;                   // P-frags of tile is-1 (carried)
    int vprev = 2, vcur = 0, vnext = 1;

    const int krow = sh * 32 + l31;      // K A-frag LDS row (sigma applied on write)
    const int kx   = kap(krow);
    const int vx0  = kap(l31);
    const int vx1  = kap(32 + l31);

    for (int is = 0; is < NSTEPS; ++is) {
        const __bf16* kb = (is & 1) ? k1 : k0;

        // global prefetch of tile is+1 (stager waves only)
        float4 pr[4];
        if (stager && is < NSTEPS - 1) {
            const int s0n = (is + 1) * 64;
            #pragma unroll
            for (int jj = 0; jj < 4; ++jj)
                pr[jj] = *(const float4*)(gsrc + (c0 + jj) * 1024 + s0n + si * 4);
        }

        // ---- S^T tile [32s][32t]: 4 chained MFMAs over c ----
        floatx16 St = ZERO16;
        #pragma unroll
        for (int kc = 0; kc < 4; ++kc) {
            bf16_8 kf = *(const bf16_8*)&kb[krow * STR + ((((kc << 1) | hv) ^ kx) << 3)];
            St = __builtin_amdgcn_mfma_f32_32x32x16_bf16(kf, qf[kc], St, 0, 0, 0);
        }

        // ---- P = exp2(S^T) -> packed B-frags, fully in-register (sigma magic) ----
        U8 w0, w1;
        #pragma unroll
        for (int d = 0; d < 4; ++d) {
            float pa = EXP2(St[2 * d]);
            float pb = EXP2(St[2 * d + 1]);
            float pc = EXP2(St[8 + 2 * d]);
            float pd = EXP2(St[8 + 2 * d + 1]);
            l += (pa + pb) + (pc + pd);
            w0.u[d] = pk_bf16(pa, pb);
            w1.u[d] = pk_bf16(pc, pd);
        }
        bf16_8 pfn0 = w0.v, pfn1 = w1.v;

        // ---- PV_{is-1} (independent of QK_is/softmax_is -> fills latency) ----
        if (is > 0) {
            const __bf16* vp = (vprev == 0) ? v0 : ((vprev == 1) ? v1 : v2);
            {
                int vrow = l31;
                bf16_8 vfa = *(const bf16_8*)&vp[vrow * STR + ((((sh << 2) | hv) ^ vx0) << 3)];
                O0 = __builtin_amdgcn_mfma_f32_32x32x16_bf16(vfa, pfp0, O0, 0, 0, 0);
                bf16_8 vfb = *(const bf16_8*)&vp[vrow * STR + ((((sh << 2) | 2 | hv) ^ vx0) << 3)];
                O0 = __builtin_amdgcn_mfma_f32_32x32x16_bf16(vfb, pfp1, O0, 0, 0, 0);
            }
            {
                int vrow = 32 + l31;
                bf16_8 vfa = *(const bf16_8*)&vp[vrow * STR + ((((sh << 2) | hv) ^ vx1) << 3)];
                O1 = __builtin_amdgcn_mfma_f32_32x32x16_bf16(vfa, pfp0, O1, 0, 0, 0);
                bf16_8 vfb = *(const bf16_8*)&vp[vrow * STR + ((((sh << 2) | 2 | hv) ^ vx1) << 3)];
                O1 = __builtin_amdgcn_mfma_f32_32x32x16_bf16(vfb, pfp1, O1, 0, 0, 0);
            }
        }
        pfp0 = pfn0; pfp1 = pfn1;

        // ---- staging of tile is+1 (K -> (is+1)&1, V -> vnext) ----
        if (is < NSTEPS - 1) {
            if (stager) {
                if (tid < 256) {
                    __bf16* kn = (is & 1) ? k0 : k1;
                    write_k(kn, pr, si, sG);
                } else {
                    __bf16* vn = (vnext == 0) ? v0 : ((vnext == 1) ? v1 : v2);
                    write_v(vn, pr, si, c0);
                }
            }
            __syncthreads();             // publish is+1, retire reads of K_is / V_{is-1}
        }
        vprev = vcur; vcur = vnext; vnext = (vnext == 2) ? 0 : vnext + 1;
    }

    // ---- final PV for tile 15 (buffer v0 = vprev after 16 rotations) ----
    {
        const __bf16* vp = (vprev == 0) ? v0 : ((vprev == 1) ? v1 : v2);
        {
            int vrow = l31;
            bf16_8 vfa = *(const bf16_8*)&vp[vrow * STR + ((((sh << 2) | hv) ^ vx0) << 3)];
            O0 = __builtin_amdgcn_mfma_f32_32x32x16_bf16(vfa, pfp0, O0, 0, 0, 0);
            bf16_8 vfb = *(const bf16_8*)&vp[vrow * STR + ((((sh << 2) | 2 | hv) ^ vx0) << 3)];
            O0 = __builtin_amdgcn_mfma_f32_32x32x16_bf16(vfb, pfp1, O0, 0, 0, 0);
        }
        {
            int vrow = 32 + l31;
            bf16_8 vfa = *(const bf16_8*)&vp[vrow * STR + ((((sh << 2) | hv) ^ vx1) << 3)];
            O1 = __builtin_amdgcn_mfma_f32_32x32x16_bf16(vfa, pfp0, O1, 0, 0, 0);
            bf16_8 vfb = *(const bf16_8*)&vp[vrow * STR + ((((sh << 2) | 2 | hv) ^ vx1) << 3)];
            O1 = __builtin_amdgcn_mfma_f32_32x32x16_bf16(vfb, pfp1, O1, 0, 0, 0);
        }
    }

    // ---- epilogue: combine s-halves (partner waves), normalize, store O^T ----
    l += __shfl_xor(l, 32);              // add other lane-half's s-contribution

    __syncthreads();                     // PV reads retired; repurpose k0..v2 (not v0)
    float* xo = (float*)smem;            // 8 groups x 4KB partial-O exchange @0..32768
    float* xl = (float*)(smem + 40960);  // l exchange (beyond v0)
    float* b  = xo + g * 1024;

    // pass 1: O0 partials + l
    if (sh == 1) {
        #pragma unroll
        for (int rq = 0; rq < 4; ++rq) {
            floatx4 a0 = {O0[4 * rq], O0[4 * rq + 1], O0[4 * rq + 2], O0[4 * rq + 3]};
            *(floatx4*)&b[(rq * 64 + lane) * 4] = a0;
        }
        xl[g * 64 + lane] = l;
    }
    __syncthreads();
    float linv = 0.f;
    float* og = out + (size_t)bh * 65536 + t0 + g * 32;
    if (sh == 0) {
        const float lt = l + xl[g * 64 + lane];
        linv = 1.0f / lt;
        #pragma unroll
        for (int rq = 0; rq < 4; ++rq) {
            floatx4 a0 = *(const floatx4*)&b[(rq * 64 + lane) * 4];
            #pragma unroll
            for (int j = 0; j < 4; ++j) {
                int cl = j + 8 * rq + 4 * hv;       // C-layout row within c-tile
                og[cl * 1024 + l31] = (O0[4 * rq + j] + a0[j]) * linv;
            }
        }
    }
    __syncthreads();
    // pass 2: O1 partials
    if (sh == 1) {
        #pragma unroll
        for (int rq = 0; rq < 4; ++rq) {
            floatx4 a1 = {O1[4 * rq], O1[4 * rq + 1], O1[4 * rq + 2], O1[4 * rq + 3]};
            *(floatx4*)&b[(rq * 64 + lane) * 4] = a1;
        }
    }
    __syncthreads();
    if (sh == 0) {
        #pragma unroll
        for (int rq = 0; rq < 4; ++rq) {
            floatx4 a1 = *(const floatx4*)&b[(rq * 64 + lane) * 4];
            #pragma unroll
            for (int j = 0; j < 4; ++j) {
                int cl = j + 8 * rq + 4 * hv;
                og[(32 + cl) * 1024 + l31] = (O1[4 * rq + j] + a1[j]) * linv;
            }
        }
    }
}

extern "C" void kernel_launch(void* const* d_in, const int* in_sizes, int n_in,
                              void* d_out, int out_size, void* d_ws, size_t ws_size,
                              hipStream_t stream) {
    const float* qkv = (const float*)d_in[0];
    float* out = (float*)d_out;
    attn_kernel<<<dim3(256), dim3(NTHREADS), 0, stream>>>(qkv, out);
}